// Round 2
// baseline (541.039 us; speedup 1.0000x reference)
//
#include <hip/hip_runtime.h>
#include <hip/hip_bf16.h>
#include <cstdint>

// LSTMCell B=4096, IN=H=2048. Pipeline: probe -> convert(fp32->bf16, concat
// layout) -> FUSED 256x(64x4gates) 8-phase bf16 GEMM + LSTM pointwise epilogue.
// Fallback (small ws): R3's ds_write GEMM + separate pointwise.

#define B_DIM 4096
#define K_DIM 2048            // IN == H
#define NG    8192            // 4*H
#define BHT   (B_DIM * K_DIM) // B*H elements per output tensor

// ws element-layout (bf16 elements) for the fast path:
//   A [4096][4096] = [X | H] rows, at 0                  (16M els, 32 MB)
//   W [8192][4096] = [Wx_g | Wh_g] row g*2048+j, at 16M  (32M els, 64 MB)
#define CONV_W_ELS  (16u << 20)
#define CONV_TOTAL  (48u << 20)             // 48M els = 96 MB
#define FAST_NEED   ((size_t)CONV_TOTAL * 2 + 65536)  // 96 MB + pad (overstage reads)

#define NTILE 64              // K tiles: 4096 / 64

using bf16x8_t  = __attribute__((ext_vector_type(8))) __bf16;
using floatx4_t = __attribute__((ext_vector_type(4))) float;
using ushort8_t = __attribute__((ext_vector_type(8))) unsigned short;

__device__ __forceinline__ float bf_bits2f(unsigned short u) {
    return __builtin_bit_cast(float, ((unsigned int)u) << 16);
}
__device__ __forceinline__ unsigned short f2bf_bits(float f) {
    return __builtin_bit_cast(unsigned short, __float2bfloat16(f));
}
__device__ __forceinline__ float sigmoid_f(float x) {
    return 1.0f / (1.0f + __expf(-x));
}
__device__ __forceinline__ float tanh_f(float x) {
    float ax = fabsf(x);
    float e  = __expf(-2.0f * ax);
    float t  = (1.0f - e) / (1.0f + e);
    return copysignf(t, x);
}

// ---------------------------------------------------------------------------
// Dtype probe: flag 0 = bf16, 1 = fp32.
// ---------------------------------------------------------------------------
__global__ void dtype_probe_kernel(const unsigned int* __restrict__ X,
                                   int* __restrict__ flag) {
    const int lane = threadIdx.x;             // 64 threads, 1 block
    const unsigned int w = X[lane];
    const unsigned short hi = (unsigned short)(w >> 16);
    const unsigned short lo = (unsigned short)(w & 0xFFFFu);
    auto sane = [](unsigned short h) -> int {
        const int e = (h >> 7) & 0xFF;
        return (e >= 90 && e <= 140) || ((h & 0x7FFF) == 0);
    };
    const unsigned long long bh = __ballot(sane(hi));
    const unsigned long long bl = __ballot(sane(lo));
    if (lane == 0) {
        const int cnt = __popcll(bh) + __popcll(bl);  // bf16 ~128, fp32 ~77
        *flag = (cnt >= 112) ? 0 : 1;
    }
}

// ---------------------------------------------------------------------------
// Convert pre-pass: build concat layout. Dest rows are 4096 els; a 2048-el
// block covers exactly one half-row -> block-uniform source.
// ---------------------------------------------------------------------------
struct SrcPtrs { const void* p[10]; };

__global__ __launch_bounds__(256) void convert_kernel(
    SrcPtrs srcs, unsigned short* __restrict__ dst,
    const int* __restrict__ flagp)
{
    const int isF32 = *flagp;
    const unsigned int idx8 = (blockIdx.x * 256u + threadIdx.x) * 8u;
    const unsigned int row = idx8 >> 12;      // dest row (4096 els each)
    const unsigned int col = idx8 & 4095u;
    int ti; size_t soff;
    if (row < 4096u) {                        // A region: [X | H]
        ti = (col < 2048u) ? 0 : 1;
        soff = (size_t)row * 2048 + (col & 2047u);
    } else {                                  // W region: [Wx_g | Wh_g]
        const unsigned int wrow = row - 4096u;
        const int gate = (int)(wrow >> 11);
        ti = (col < 2048u) ? (2 + gate) : (6 + gate);
        soff = (size_t)(wrow & 2047u) * 2048 + (col & 2047u);
    }

    ushort8_t v;
    if (isF32) {
        const float* s = (const float*)srcs.p[ti] + soff;
        const float4 f0 = *reinterpret_cast<const float4*>(s);
        const float4 f1 = *reinterpret_cast<const float4*>(s + 4);
        v = (ushort8_t){f2bf_bits(f0.x), f2bf_bits(f0.y), f2bf_bits(f0.z), f2bf_bits(f0.w),
                        f2bf_bits(f1.x), f2bf_bits(f1.y), f2bf_bits(f1.z), f2bf_bits(f1.w)};
    } else {
        v = *reinterpret_cast<const ushort8_t*>((const unsigned short*)srcs.p[ti] + soff);
    }
    *reinterpret_cast<ushort8_t*>(dst + idx8) = v;
}

// ---------------------------------------------------------------------------
// Fused GEMM+LSTM: 256 rows x 64 H-cols x 4 gates per block, BK=64, 512 thr =
// 8 waves (2Mx4N), 8-phase schedule (T2 swizzle + counted vmcnt + setprio).
// B-tile rows 0..255 = {gate=r>>6, col=bn*64+(r&63)} of W. The 4 "ni" frag
// slots are the 4 gates -> acc[a][g] holds (i,o,f,c) per (row,col) in fp32,
// LSTM pointwise applied in epilogue. XCD-chunked block swizzle (T1).
// ---------------------------------------------------------------------------
#define GLL(SRC, DST) \
  __builtin_amdgcn_global_load_lds( \
      (const __attribute__((address_space(1))) void*)(SRC), \
      (__attribute__((address_space(3))) void*)(DST), 16, 0, 0)

#define STAGE_A(KOFF, BUF, KS) do { \
    GLL(pA0 + (KOFF), lds + ((BUF) * 2 + (KS)) * 16384 + wvOff); \
    GLL(pA1 + (KOFF), lds + ((BUF) * 2 + (KS)) * 16384 + 8192 + wvOff); \
  } while (0)

#define STAGE_B(KOFF, BUF, KS) do { \
    GLL(pB0 + (KOFF), lds + 65536 + ((BUF) * 2 + (KS)) * 16384 + wvOff); \
    GLL(pB1 + (KOFF), lds + 65536 + ((BUF) * 2 + (KS)) * 16384 + 8192 + wvOff); \
  } while (0)

// Phase: {ds_read frags | stage 1 half | barrier | lgkmcnt(0) | setprio(1)
//         16 MFMA | setprio(0) | [vmcnt(4)] | barrier}
#define PHASE(BUF, KS, MH, DOB, STAGE_STMT, DOVM) \
  { \
    const char* aSlot_ = lds + ((BUF) * 2 + (KS)) * 16384 + (MH) * 4096; \
    _Pragma("unroll") \
    for (int i_ = 0; i_ < 4; ++i_) \
      af[i_] = *reinterpret_cast<const bf16x8_t*>(aSlot_ + aoff[i_]); \
    if (DOB) { \
      const char* bSlot_ = lds + 65536 + ((BUF) * 2 + (KS)) * 16384; \
      _Pragma("unroll") \
      for (int i_ = 0; i_ < 4; ++i_) \
        bw[i_] = *reinterpret_cast<const bf16x8_t*>(bSlot_ + boff[i_]); \
    } \
    STAGE_STMT; \
    __builtin_amdgcn_s_barrier(); \
    asm volatile("s_waitcnt lgkmcnt(0)" ::: "memory"); \
    __builtin_amdgcn_s_setprio(1); \
    _Pragma("unroll") \
    for (int mi_ = 0; mi_ < 4; ++mi_) \
      _Pragma("unroll") \
      for (int ni_ = 0; ni_ < 4; ++ni_) \
        acc[(MH) * 4 + mi_][ni_] = __builtin_amdgcn_mfma_f32_16x16x32_bf16( \
            af[mi_], bw[ni_], acc[(MH) * 4 + mi_][ni_], 0, 0, 0); \
    __builtin_amdgcn_s_setprio(0); \
    if (DOVM) asm volatile("s_waitcnt vmcnt(4)" ::: "memory"); \
    __builtin_amdgcn_s_barrier(); \
  }

__global__ __launch_bounds__(512, 2) void gates_gemm_fast(
    const unsigned short* __restrict__ conv,
    const void* __restrict__ bi0, const void* __restrict__ bi1,
    const void* __restrict__ bi2, const void* __restrict__ bi3,
    const void* __restrict__ Cin,
    const int* __restrict__ flagp,
    void* __restrict__ outp)                  // h [4096,2048], c follows
{
    __shared__ __align__(16) char lds[131072];   // A: 4x16K, B: 4x16K

    const int tid = threadIdx.x;
    // T1 XCD-chunked swizzle: 512 blocks, 8 XCDs -> each XCD gets 64
    // contiguous nids (= 2 bm rows x all 32 bn) -> one A-panel L2-resident
    // per XCD per round.
    const int orig = blockIdx.x;              // 0..511
    const int nid  = (orig & 7) * 64 + (orig >> 3);
    const int bn   = nid & 31;                // H-column tile (64 cols)
    const int bm   = nid >> 5;                // M tile (256 rows)

    const char* Ab = (const char*)conv;                    // [4096][4096] bf16
    const char* Wb = (const char*)(conv + CONV_W_ELS);     // [8192][4096] bf16

    // Staging source: thread t, call c writes LDS linear o = c*8192 + t*16;
    // it must carry the element whose logical in-slot offset is swz(o).
    const int o0   = tid << 4;
    const int l0   = o0 ^ (((o0 >> 7) & 3) << 4);
    const int srow = l0 >> 6;                 // 0..127
    const int skb  = l0 & 63;
    const char* pA0 = Ab + ((size_t)(bm * 256 + srow)) * 8192 + skb;
    const char* pA1 = pA0 + (size_t)128 * 8192;
    // B-tile row r: gate r>>6, W row (r>>6)*2048 + bn*64 + (r&63).
    const int br1 = srow + 128;
    const char* pB0 = Wb + ((size_t)((srow >> 6) * 2048 + bn * 64 + (srow & 63))) * 8192 + skb;
    const char* pB1 = Wb + ((size_t)((br1  >> 6) * 2048 + bn * 64 + (br1  & 63))) * 8192 + skb;

    const int waveU = __builtin_amdgcn_readfirstlane(tid >> 6);
    const int wvOff = waveU * 1024;
    const int lane = tid & 63;
    const int lr   = lane & 15;
    const int quad = lane >> 4;
    const int wid  = tid >> 6;                // 0..7
    const int wr   = wid >> 2;                // 0..1  (M half)
    const int wc   = wid & 3;                 // 0..3  (16-col quarter)

    // Swizzled in-slot ds_read offsets. B frag g (gate) reads tile rows
    // g*64 + wc*16 + lr.
    int aoff[4], boff[4];
#pragma unroll
    for (int i = 0; i < 4; ++i) {
        int xa = (wr * 128 + i * 16 + lr) * 64 + quad * 16;
        aoff[i] = xa ^ (((xa >> 7) & 3) << 4);
        int xb = (i * 64 + wc * 16 + lr) * 64 + quad * 16;
        boff[i] = xb ^ (((xb >> 7) & 3) << 4);
    }

    floatx4_t acc[8][4];
#pragma unroll
    for (int a = 0; a < 8; ++a)
#pragma unroll
        for (int g = 0; g < 4; ++g)
            acc[a][g] = (floatx4_t){0.f, 0.f, 0.f, 0.f};

    // Prologue: tile0 (k0,k1) + tile1 (k0); vmcnt(4) => tile0 fully landed.
    STAGE_A(0, 0, 0);   STAGE_B(0, 0, 0);
    STAGE_A(64, 0, 1);  STAGE_B(64, 0, 1);
    STAGE_A(128, 1, 0); STAGE_B(128, 1, 0);
    asm volatile("s_waitcnt vmcnt(4)" ::: "memory");
    __builtin_amdgcn_s_barrier();

    // Steady state per iter (tiles t=2i in buf0, t+1 in buf1):
    //  P1 rd buf0k0, st A(t+1,k1)->b1k1   P5 rd buf1k0, st A(t+2,k1)->b0k1
    //  P2 rd buf0k0, st B(t+1,k1)         P6 rd buf1k0, st B(t+2,k1)
    //  P3 rd buf0k1, st A(t+2,k0)->b0k0   P7 rd buf1k1, st A(t+3,k0)->b1k0
    //  P4 rd buf0k1, st B(t+2,k0); vm4    P8 rd buf1k1, st B(t+3,k0); vm4
    // W-A-R: every stage targets a slot last read >=1 barrier earlier.
    // R-A-W: vm4@P4 covers P5/P7 data; vm4@P8 covers next-iter P1/P3 data.
    // Last iter stages harmless in-bounds garbage (<=8.5KB past W end; ws
    // has a 64KB pad).
    bf16x8_t af[4], bw[4];
#pragma unroll 1
    for (int it2 = 0; it2 < NTILE / 2; ++it2) {
        const int kt = it2 * 256;             // byte k-offset of tile t=2*it2
        PHASE(0, 0, 0, 1, STAGE_A(kt + 192, 1, 1), 0)
        PHASE(0, 0, 1, 0, STAGE_B(kt + 192, 1, 1), 0)
        PHASE(0, 1, 0, 1, STAGE_A(kt + 256, 0, 0), 0)
        PHASE(0, 1, 1, 0, STAGE_B(kt + 256, 0, 0), 1)
        PHASE(1, 0, 0, 1, STAGE_A(kt + 320, 0, 1), 0)
        PHASE(1, 0, 1, 0, STAGE_B(kt + 320, 0, 1), 0)
        PHASE(1, 1, 0, 1, STAGE_A(kt + 384, 1, 0), 0)
        PHASE(1, 1, 1, 0, STAGE_B(kt + 384, 1, 0), 1)
    }
    asm volatile("s_waitcnt vmcnt(0)" ::: "memory");  // drain garbage stages

    // Fused epilogue: gates in fp32 -> sigmoid/tanh -> read C -> write h,c.
    // C/D layout: col=lane&15, row=quad*4+reg (m89).
    const int isF32 = *flagp;
    const int col = bn * 64 + wc * 16 + lr;   // H column, 0..2047
    float bvv[4];
    bvv[0] = isF32 ? ((const float*)bi0)[col] : __bfloat162float(((const __hip_bfloat16*)bi0)[col]);
    bvv[1] = isF32 ? ((const float*)bi1)[col] : __bfloat162float(((const __hip_bfloat16*)bi1)[col]);
    bvv[2] = isF32 ? ((const float*)bi2)[col] : __bfloat162float(((const __hip_bfloat16*)bi2)[col]);
    bvv[3] = isF32 ? ((const float*)bi3)[col] : __bfloat162float(((const __hip_bfloat16*)bi3)[col]);

#pragma unroll
    for (int a = 0; a < 8; ++a) {
        const int rowBase = bm * 256 + wr * 128 + (a >> 2) * 64 + (a & 3) * 16 + quad * 4;
#pragma unroll
        for (int r = 0; r < 4; ++r) {
            const size_t idx = (size_t)(rowBase + r) * K_DIM + col;
            const float gi = acc[a][0][r] + bvv[0];
            const float go = acc[a][1][r] + bvv[1];
            const float gf = acc[a][2][r] + bvv[2];
            const float gc = acc[a][3][r] + bvv[3];
            const float cv = isF32 ? ((const float*)Cin)[idx]
                                   : bf_bits2f(((const unsigned short*)Cin)[idx]);
            const float it = sigmoid_f(gi);
            const float ot = sigmoid_f(go);
            const float ft = sigmoid_f(gf);
            const float ct = tanh_f(gc);
            const float nc = ft * cv + it * ct;
            const float nh = ot * tanh_f(nc);
            if (isF32) {
                ((float*)outp)[idx] = nh;
                ((float*)outp)[(size_t)BHT + idx] = nc;
            } else {
                ((unsigned short*)outp)[idx] = f2bf_bits(nh);
                ((unsigned short*)outp)[(size_t)BHT + idx] = f2bf_bits(nc);
            }
        }
    }
}

// ---------------------------------------------------------------------------
// Slow fallback GEMM (R3, passed): ds_write staging + in-kernel conversion.
// ---------------------------------------------------------------------------
__global__ __launch_bounds__(256) void gates_gemm_slow(
    const void* __restrict__ X, const void* __restrict__ Hm,
    const void* __restrict__ Wx0, const void* __restrict__ Wx1,
    const void* __restrict__ Wx2, const void* __restrict__ Wx3,
    const void* __restrict__ Wh0, const void* __restrict__ Wh1,
    const void* __restrict__ Wh2, const void* __restrict__ Wh3,
    const void* __restrict__ bi0, const void* __restrict__ bi1,
    const void* __restrict__ bi2, const void* __restrict__ bi3,
    const int* __restrict__ flagp, int m0,
    __hip_bfloat16* __restrict__ gates)
{
    __shared__ __align__(16) char lds[16384];
    const int isF32 = *flagp;
    const int esz   = isF32 ? 4 : 2;

    const int tid     = threadIdx.x;
    const int bm      = blockIdx.y;
    const int bn      = blockIdx.x;
    const int gate    = bn >> 4;
    const int nInGate = (bn & 15) << 7;

    const void* Wx = (gate == 0) ? Wx0 : (gate == 1) ? Wx1 : (gate == 2) ? Wx2 : Wx3;
    const void* Wh = (gate == 0) ? Wh0 : (gate == 1) ? Wh1 : (gate == 2) ? Wh2 : Wh3;
    const void* bs = (gate == 0) ? bi0 : (gate == 1) ? bi1 : (gate == 2) ? bi2 : bi3;

    const int ldRow = tid >> 2;
    const int sub   = tid & 3;
    const size_t rowStride = (size_t)K_DIM * esz;
    const size_t rowHalf   = 64 * rowStride;
    const char* aG  = (const char*)X  + (size_t)(m0 + bm * 128 + ldRow) * rowStride + (size_t)sub * 8 * esz;
    const char* hG  = (const char*)Hm + (size_t)(m0 + bm * 128 + ldRow) * rowStride + (size_t)sub * 8 * esz;
    const char* wxG = (const char*)Wx + (size_t)(nInGate + ldRow) * rowStride + (size_t)sub * 8 * esz;
    const char* whG = (const char*)Wh + (size_t)(nInGate + ldRow) * rowStride + (size_t)sub * 8 * esz;

    char* const dA0 = lds + tid * 16;
    char* const dA1 = lds + 4096 + tid * 16;
    char* const dB0 = lds + 8192 + tid * 16;
    char* const dB1 = lds + 12288 + tid * 16;
    const char* const AsB = lds;
    const char* const BsB = lds + 8192;

    const int lane = tid & 63;
    const int wave = tid >> 6;
    const int wm   = (wave & 1) << 6;
    const int wn   = (wave >> 1) << 6;
    const int lr   = lane & 15;
    const int quad = lane >> 4;

    int aOff[4], bOff[4];
#pragma unroll
    for (int i = 0; i < 4; ++i) {
        aOff[i] = ((wm + i * 16 + lr) * 32 + quad * 8) * 2;
        bOff[i] = ((wn + i * 16 + lr) * 32 + quad * 8) * 2;
    }

    floatx4_t acc[4][4];
#pragma unroll
    for (int mi = 0; mi < 4; ++mi)
#pragma unroll
        for (int ni = 0; ni < 4; ++ni)
            acc[mi][ni] = (floatx4_t){0.f, 0.f, 0.f, 0.f};

#pragma unroll 1
    for (int seg = 0; seg < 2; ++seg) {
        const char* ag = seg ? hG : aG;
        const char* bg = seg ? whG : wxG;
#pragma unroll 1
        for (int ke = 0; ke < K_DIM; ke += 32) {
            const size_t kb = (size_t)ke * esz;
            ushort8_t va0, va1, vb0, vb1;
            if (!isF32) {
                va0 = *reinterpret_cast<const ushort8_t*>(ag + kb);
                va1 = *reinterpret_cast<const ushort8_t*>(ag + rowHalf + kb);
                vb0 = *reinterpret_cast<const ushort8_t*>(bg + kb);
                vb1 = *reinterpret_cast<const ushort8_t*>(bg + rowHalf + kb);
            } else {
                const char* p; float4 f0, f1;
                p = ag + kb;           f0 = *reinterpret_cast<const float4*>(p);
                f1 = *reinterpret_cast<const float4*>(p + 16);
                va0 = (ushort8_t){f2bf_bits(f0.x), f2bf_bits(f0.y), f2bf_bits(f0.z), f2bf_bits(f0.w),
                                  f2bf_bits(f1.x), f2bf_bits(f1.y), f2bf_bits(f1.z), f2bf_bits(f1.w)};
                p = ag + rowHalf + kb; f0 = *reinterpret_cast<const float4*>(p);
                f1 = *reinterpret_cast<const float4*>(p + 16);
                va1 = (ushort8_t){f2bf_bits(f0.x), f2bf_bits(f0.y), f2bf_bits(f0.z), f2bf_bits(f0.w),
                                  f2bf_bits(f1.x), f2bf_bits(f1.y), f2bf_bits(f1.z), f2bf_bits(f1.w)};
                p = bg + kb;           f0 = *reinterpret_cast<const float4*>(p);
                f1 = *reinterpret_cast<const float4*>(p + 16);
                vb0 = (ushort8_t){f2bf_bits(f0.x), f2bf_bits(f0.y), f2bf_bits(f0.z), f2bf_bits(f0.w),
                                  f2bf_bits(f1.x), f2bf_bits(f1.y), f2bf_bits(f1.z), f2bf_bits(f1.w)};
                p = bg + rowHalf + kb; f0 = *reinterpret_cast<const float4*>(p);
                f1 = *reinterpret_cast<const float4*>(p + 16);
                vb1 = (ushort8_t){f2bf_bits(f0.x), f2bf_bits(f0.y), f2bf_bits(f0.z), f2bf_bits(f0.w),
                                  f2bf_bits(f1.x), f2bf_bits(f1.y), f2bf_bits(f1.z), f2bf_bits(f1.w)};
            }
            __syncthreads();
            *reinterpret_cast<ushort8_t*>(dA0) = va0;
            *reinterpret_cast<ushort8_t*>(dA1) = va1;
            *reinterpret_cast<ushort8_t*>(dB0) = vb0;
            *reinterpret_cast<ushort8_t*>(dB1) = vb1;
            __syncthreads();

            bf16x8_t af[4], bwv[4];
#pragma unroll
            for (int i = 0; i < 4; ++i) af[i] = *reinterpret_cast<const bf16x8_t*>(AsB + aOff[i]);
#pragma unroll
            for (int i = 0; i < 4; ++i) bwv[i] = *reinterpret_cast<const bf16x8_t*>(BsB + bOff[i]);
#pragma unroll
            for (int mi = 0; mi < 4; ++mi)
#pragma unroll
                for (int ni = 0; ni < 4; ++ni)
                    acc[mi][ni] = __builtin_amdgcn_mfma_f32_16x16x32_bf16(
                        af[mi], bwv[ni], acc[mi][ni], 0, 0, 0);
        }
    }

    float bv[4];
#pragma unroll
    for (int ni = 0; ni < 4; ++ni) {
        const int col = nInGate + wn + ni * 16 + lr;
        bv[ni] = isF32 ? ((const float*)bs)[col]
                       : __bfloat162float(((const __hip_bfloat16*)bs)[col]);
    }
#pragma unroll
    for (int mi = 0; mi < 4; ++mi) {
        const int rowBase = bm * 128 + wm + mi * 16 + quad * 4;
#pragma unroll
        for (int ni = 0; ni < 4; ++ni) {
            const size_t colBase = (size_t)gate * 2048 + nInGate + wn + ni * 16 + lr;
#pragma unroll
            for (int r = 0; r < 4; ++r)
                gates[(size_t)(rowBase + r) * NG + colBase] =
                    __float2bfloat16(acc[mi][ni][r] + bv[ni]);
        }
    }
}

// ---------------------------------------------------------------------------
// Pointwise LSTM combine (fallback path only).
// ---------------------------------------------------------------------------
__global__ __launch_bounds__(256) void lstm_pointwise_kernel(
    const unsigned short* __restrict__ gates,
    const void* __restrict__ Cin,
    void* __restrict__ out,
    const int* __restrict__ flagp, int m0)
{
    const int isF32 = *flagp;
    const int lidx = (blockIdx.x * 256 + threadIdx.x) * 4;
    const int b = lidx >> 11;
    const int j = lidx & 2047;
    const unsigned short* g = gates + (size_t)b * NG + j;
    const size_t gidx = (size_t)m0 * 2048 + (size_t)lidx;

    const ushort4 ui = *reinterpret_cast<const ushort4*>(g);
    const ushort4 uo = *reinterpret_cast<const ushort4*>(g + 2048);
    const ushort4 uf = *reinterpret_cast<const ushort4*>(g + 4096);
    const ushort4 uc = *reinterpret_cast<const ushort4*>(g + 6144);
    const float gi[4] = {bf_bits2f(ui.x), bf_bits2f(ui.y), bf_bits2f(ui.z), bf_bits2f(ui.w)};
    const float go[4] = {bf_bits2f(uo.x), bf_bits2f(uo.y), bf_bits2f(uo.z), bf_bits2f(uo.w)};
    const float gf[4] = {bf_bits2f(uf.x), bf_bits2f(uf.y), bf_bits2f(uf.z), bf_bits2f(uf.w)};
    const float gc[4] = {bf_bits2f(uc.x), bf_bits2f(uc.y), bf_bits2f(uc.z), bf_bits2f(uc.w)};

    float cv[4];
    if (isF32) {
        const float4 c4 = *reinterpret_cast<const float4*>((const float*)Cin + gidx);
        cv[0] = c4.x; cv[1] = c4.y; cv[2] = c4.z; cv[3] = c4.w;
    } else {
        const ushort4 u = *reinterpret_cast<const ushort4*>((const unsigned short*)Cin + gidx);
        cv[0] = bf_bits2f(u.x); cv[1] = bf_bits2f(u.y);
        cv[2] = bf_bits2f(u.z); cv[3] = bf_bits2f(u.w);
    }

    float nh[4], nc[4];
#pragma unroll
    for (int k = 0; k < 4; ++k) {
        const float it = sigmoid_f(gi[k]);
        const float ot = sigmoid_f(go[k]);
        const float ft = sigmoid_f(gf[k]);
        const float ct = tanh_f(gc[k]);
        nc[k] = ft * cv[k] + it * ct;
        nh[k] = ot * tanh_f(nc[k]);
    }

    if (isF32) {
        float* oH = (float*)out;
        float* oC = oH + (size_t)BHT;
        *reinterpret_cast<float4*>(oH + gidx) = make_float4(nh[0], nh[1], nh[2], nh[3]);
        *reinterpret_cast<float4*>(oC + gidx) = make_float4(nc[0], nc[1], nc[2], nc[3]);
    } else {
        unsigned short* oH = (unsigned short*)out;
        unsigned short* oC = oH + (size_t)BHT;
        *reinterpret_cast<ushort4*>(oH + gidx) =
            make_ushort4(f2bf_bits(nh[0]), f2bf_bits(nh[1]), f2bf_bits(nh[2]), f2bf_bits(nh[3]));
        *reinterpret_cast<ushort4*>(oC + gidx) =
            make_ushort4(f2bf_bits(nc[0]), f2bf_bits(nc[1]), f2bf_bits(nc[2]), f2bf_bits(nc[3]));
    }
}

extern "C" void kernel_launch(void* const* d_in, const int* in_sizes, int n_in,
                              void* d_out, int out_size, void* d_ws, size_t ws_size,
                              hipStream_t stream) {
    (void)in_sizes; (void)n_in; (void)out_size;
    const void* X   = d_in[0];
    const void* Hm  = d_in[1];
    const void* C   = d_in[2];
    const void* Wxi = d_in[3];
    const void* Wxo = d_in[4];
    const void* Wxf = d_in[5];
    const void* Wxc = d_in[6];
    const void* bi  = d_in[7];
    const void* bo  = d_in[8];
    const void* bfp = d_in[9];
    const void* bc  = d_in[10];
    const void* Whi = d_in[11];
    const void* Who = d_in[12];
    const void* Whf = d_in[13];
    const void* Whc = d_in[14];

    const size_t flagOff = (ws_size - 4) & ~(size_t)15;
    int* flag = (int*)((char*)d_ws + flagOff);
    const dim3 blk(256);

    dtype_probe_kernel<<<1, 64, 0, stream>>>((const unsigned int*)X, flag);

    if (ws_size >= FAST_NEED) {
        unsigned short* conv = (unsigned short*)d_ws;

        SrcPtrs sp;
        sp.p[0] = X;  sp.p[1] = Hm;
        sp.p[2] = Wxi; sp.p[3] = Wxo; sp.p[4] = Wxf; sp.p[5] = Wxc;
        sp.p[6] = Whi; sp.p[7] = Who; sp.p[8] = Whf; sp.p[9] = Whc;
        convert_kernel<<<dim3(CONV_TOTAL / 2048), blk, 0, stream>>>(sp, conv, flag);

        gates_gemm_fast<<<dim3(512), dim3(512), 0, stream>>>(
            conv, bi, bo, bfp, bc, C, flag, d_out);
    } else {
        __hip_bfloat16* gates = (__hip_bfloat16*)d_ws;
        int rows = B_DIM;
        while ((size_t)rows * NG * 2 > flagOff && rows > 128) rows >>= 1;
        for (int m0 = 0; m0 < B_DIM; m0 += rows) {
            gates_gemm_slow<<<dim3(64, rows / 128), blk, 0, stream>>>(
                X, Hm, Wxi, Wxo, Wxf, Wxc, Whi, Who, Whf, Whc,
                bi, bo, bfp, bc, flag, m0, gates);
            lstm_pointwise_kernel<<<dim3(rows * 2048 / 1024), blk, 0, stream>>>(
                (const unsigned short*)gates, C, d_out, flag, m0);
        }
    }
}

// Round 3
// 493.506 us; speedup vs baseline: 1.0963x; 1.0963x over previous
//
#include <hip/hip_runtime.h>
#include <hip/hip_bf16.h>
#include <cstdint>

// LSTMCell B=4096, IN=H=2048. Pipeline: probe -> convert(fp32->bf16, concat
// layout) -> FUSED 256x(64x4gates) 8-phase bf16 GEMM + LSTM pointwise epilogue.
// R2 lesson: block swizzle must give W (64MB, 16 readers/panel) the XCD
// affinity, not A (32MB) — W replication across 8 XCDs cost +455MB FETCH.
// Fallback (small ws): R3's ds_write GEMM + separate pointwise.

#define B_DIM 4096
#define K_DIM 2048            // IN == H
#define NG    8192            // 4*H
#define BHT   (B_DIM * K_DIM) // B*H elements per output tensor

// ws element-layout (bf16 elements) for the fast path:
//   A [4096][4096] = [X | H] rows, at 0                  (16M els, 32 MB)
//   W [8192][4096] = [Wx_g | Wh_g] row g*2048+j, at 16M  (32M els, 64 MB)
#define CONV_W_ELS  (16u << 20)
#define CONV_TOTAL  (48u << 20)             // 48M els = 96 MB
#define FAST_NEED   ((size_t)CONV_TOTAL * 2 + 65536)  // 96 MB + pad (overstage reads)

#define NTILE 64              // K tiles: 4096 / 64

using bf16x8_t  = __attribute__((ext_vector_type(8))) __bf16;
using floatx4_t = __attribute__((ext_vector_type(4))) float;
using ushort8_t = __attribute__((ext_vector_type(8))) unsigned short;

__device__ __forceinline__ float bf_bits2f(unsigned short u) {
    return __builtin_bit_cast(float, ((unsigned int)u) << 16);
}
__device__ __forceinline__ unsigned short f2bf_bits(float f) {
    return __builtin_bit_cast(unsigned short, __float2bfloat16(f));
}
__device__ __forceinline__ float sigmoid_f(float x) {
    return 1.0f / (1.0f + __expf(-x));
}
__device__ __forceinline__ float tanh_f(float x) {
    float ax = fabsf(x);
    float e  = __expf(-2.0f * ax);
    float t  = (1.0f - e) / (1.0f + e);
    return copysignf(t, x);
}

// ---------------------------------------------------------------------------
// Dtype probe: flag 0 = bf16, 1 = fp32.
// ---------------------------------------------------------------------------
__global__ void dtype_probe_kernel(const unsigned int* __restrict__ X,
                                   int* __restrict__ flag) {
    const int lane = threadIdx.x;             // 64 threads, 1 block
    const unsigned int w = X[lane];
    const unsigned short hi = (unsigned short)(w >> 16);
    const unsigned short lo = (unsigned short)(w & 0xFFFFu);
    auto sane = [](unsigned short h) -> int {
        const int e = (h >> 7) & 0xFF;
        return (e >= 90 && e <= 140) || ((h & 0x7FFF) == 0);
    };
    const unsigned long long bh = __ballot(sane(hi));
    const unsigned long long bl = __ballot(sane(lo));
    if (lane == 0) {
        const int cnt = __popcll(bh) + __popcll(bl);  // bf16 ~128, fp32 ~77
        *flag = (cnt >= 112) ? 0 : 1;
    }
}

// ---------------------------------------------------------------------------
// Convert pre-pass: build concat layout. Dest rows are 4096 els; a 2048-el
// block covers exactly one half-row -> block-uniform source.
// ---------------------------------------------------------------------------
struct SrcPtrs { const void* p[10]; };

__global__ __launch_bounds__(256) void convert_kernel(
    SrcPtrs srcs, unsigned short* __restrict__ dst,
    const int* __restrict__ flagp)
{
    const int isF32 = *flagp;
    const unsigned int idx8 = (blockIdx.x * 256u + threadIdx.x) * 8u;
    const unsigned int row = idx8 >> 12;      // dest row (4096 els each)
    const unsigned int col = idx8 & 4095u;
    int ti; size_t soff;
    if (row < 4096u) {                        // A region: [X | H]
        ti = (col < 2048u) ? 0 : 1;
        soff = (size_t)row * 2048 + (col & 2047u);
    } else {                                  // W region: [Wx_g | Wh_g]
        const unsigned int wrow = row - 4096u;
        const int gate = (int)(wrow >> 11);
        ti = (col < 2048u) ? (2 + gate) : (6 + gate);
        soff = (size_t)(wrow & 2047u) * 2048 + (col & 2047u);
    }

    ushort8_t v;
    if (isF32) {
        const float* s = (const float*)srcs.p[ti] + soff;
        const float4 f0 = *reinterpret_cast<const float4*>(s);
        const float4 f1 = *reinterpret_cast<const float4*>(s + 4);
        v = (ushort8_t){f2bf_bits(f0.x), f2bf_bits(f0.y), f2bf_bits(f0.z), f2bf_bits(f0.w),
                        f2bf_bits(f1.x), f2bf_bits(f1.y), f2bf_bits(f1.z), f2bf_bits(f1.w)};
    } else {
        v = *reinterpret_cast<const ushort8_t*>((const unsigned short*)srcs.p[ti] + soff);
    }
    *reinterpret_cast<ushort8_t*>(dst + idx8) = v;
}

// ---------------------------------------------------------------------------
// Fused GEMM+LSTM: 256 rows x 64 H-cols x 4 gates per block, BK=64, 512 thr =
// 8 waves (2Mx4N), 8-phase schedule (T2 swizzle + counted vmcnt + setprio).
// B-tile rows 0..255 = {gate=r>>6, col=bn*64+(r&63)} of W. The 4 "ni" frag
// slots are the 4 gates -> acc[a][g] holds (i,o,f,c) per (row,col) in fp32,
// LSTM pointwise applied in epilogue.
// ---------------------------------------------------------------------------
#define GLL(SRC, DST) \
  __builtin_amdgcn_global_load_lds( \
      (const __attribute__((address_space(1))) void*)(SRC), \
      (__attribute__((address_space(3))) void*)(DST), 16, 0, 0)

#define STAGE_A(KOFF, BUF, KS) do { \
    GLL(pA0 + (KOFF), lds + ((BUF) * 2 + (KS)) * 16384 + wvOff); \
    GLL(pA1 + (KOFF), lds + ((BUF) * 2 + (KS)) * 16384 + 8192 + wvOff); \
  } while (0)

#define STAGE_B(KOFF, BUF, KS) do { \
    GLL(pB0 + (KOFF), lds + 65536 + ((BUF) * 2 + (KS)) * 16384 + wvOff); \
    GLL(pB1 + (KOFF), lds + 65536 + ((BUF) * 2 + (KS)) * 16384 + 8192 + wvOff); \
  } while (0)

// Phase: {ds_read frags | stage 1 half | barrier | lgkmcnt(0) | setprio(1)
//         16 MFMA | setprio(0) | [vmcnt(4)] | barrier}
#define PHASE(BUF, KS, MH, DOB, STAGE_STMT, DOVM) \
  { \
    const char* aSlot_ = lds + ((BUF) * 2 + (KS)) * 16384 + (MH) * 4096; \
    _Pragma("unroll") \
    for (int i_ = 0; i_ < 4; ++i_) \
      af[i_] = *reinterpret_cast<const bf16x8_t*>(aSlot_ + aoff[i_]); \
    if (DOB) { \
      const char* bSlot_ = lds + 65536 + ((BUF) * 2 + (KS)) * 16384; \
      _Pragma("unroll") \
      for (int i_ = 0; i_ < 4; ++i_) \
        bw[i_] = *reinterpret_cast<const bf16x8_t*>(bSlot_ + boff[i_]); \
    } \
    STAGE_STMT; \
    __builtin_amdgcn_s_barrier(); \
    asm volatile("s_waitcnt lgkmcnt(0)" ::: "memory"); \
    __builtin_amdgcn_s_setprio(1); \
    _Pragma("unroll") \
    for (int mi_ = 0; mi_ < 4; ++mi_) \
      _Pragma("unroll") \
      for (int ni_ = 0; ni_ < 4; ++ni_) \
        acc[(MH) * 4 + mi_][ni_] = __builtin_amdgcn_mfma_f32_16x16x32_bf16( \
            af[mi_], bw[ni_], acc[(MH) * 4 + mi_][ni_], 0, 0, 0); \
    __builtin_amdgcn_s_setprio(0); \
    if (DOVM) asm volatile("s_waitcnt vmcnt(4)" ::: "memory"); \
    __builtin_amdgcn_s_barrier(); \
  }

__global__ __launch_bounds__(512, 2) void gates_gemm_fast(
    const unsigned short* __restrict__ conv,
    const void* __restrict__ bi0, const void* __restrict__ bi1,
    const void* __restrict__ bi2, const void* __restrict__ bi3,
    const void* __restrict__ Cin,
    const int* __restrict__ flagp,
    void* __restrict__ outp)                  // h [4096,2048], c follows
{
    __shared__ __align__(16) char lds[131072];   // A: 4x16K, B: 4x16K

    const int tid = threadIdx.x;
    // W-affinity swizzle: XCD = orig%8 (round-robin dispatch). All 16 readers
    // of W panel bn land on XCD bn%8 -> W fetched once per panel (like R1's
    // accidental affinity). Same-bm blocks (4 bn sharers) adjacent in time.
    const int orig = blockIdx.x;              // 0..511
    const int xq   = orig & 7;
    const int j    = orig >> 3;               // 0..63
    const int bn   = xq + ((j & 3) << 3);     // H-column tile (64 cols), 0..31
    const int bm   = j >> 2;                  // M tile (256 rows), 0..15

    const char* Ab = (const char*)conv;                    // [4096][4096] bf16
    const char* Wb = (const char*)(conv + CONV_W_ELS);     // [8192][4096] bf16

    // Staging source: thread t, call c writes LDS linear o = c*8192 + t*16;
    // it must carry the element whose logical in-slot offset is swz(o).
    const int o0   = tid << 4;
    const int l0   = o0 ^ (((o0 >> 7) & 3) << 4);
    const int srow = l0 >> 6;                 // 0..127
    const int skb  = l0 & 63;
    const char* pA0 = Ab + ((size_t)(bm * 256 + srow)) * 8192 + skb;
    const char* pA1 = pA0 + (size_t)128 * 8192;
    // B-tile row r: gate r>>6, W row (r>>6)*2048 + bn*64 + (r&63).
    const int br1 = srow + 128;
    const char* pB0 = Wb + ((size_t)((srow >> 6) * 2048 + bn * 64 + (srow & 63))) * 8192 + skb;
    const char* pB1 = Wb + ((size_t)((br1  >> 6) * 2048 + bn * 64 + (br1  & 63))) * 8192 + skb;

    const int waveU = __builtin_amdgcn_readfirstlane(tid >> 6);
    const int wvOff = waveU * 1024;
    const int lane = tid & 63;
    const int lr   = lane & 15;
    const int quad = lane >> 4;
    const int wid  = tid >> 6;                // 0..7
    const int wr   = wid >> 2;                // 0..1  (M half)
    const int wc   = wid & 3;                 // 0..3  (16-col quarter)

    // Swizzled in-slot ds_read offsets. B frag g (gate) reads tile rows
    // g*64 + wc*16 + lr.
    int aoff[4], boff[4];
#pragma unroll
    for (int i = 0; i < 4; ++i) {
        int xa = (wr * 128 + i * 16 + lr) * 64 + quad * 16;
        aoff[i] = xa ^ (((xa >> 7) & 3) << 4);
        int xb = (i * 64 + wc * 16 + lr) * 64 + quad * 16;
        boff[i] = xb ^ (((xb >> 7) & 3) << 4);
    }

    floatx4_t acc[8][4];
#pragma unroll
    for (int a = 0; a < 8; ++a)
#pragma unroll
        for (int g = 0; g < 4; ++g)
            acc[a][g] = (floatx4_t){0.f, 0.f, 0.f, 0.f};

    // Prologue: tile0 (k0,k1) + tile1 (k0); vmcnt(4) => tile0 fully landed.
    STAGE_A(0, 0, 0);   STAGE_B(0, 0, 0);
    STAGE_A(64, 0, 1);  STAGE_B(64, 0, 1);
    STAGE_A(128, 1, 0); STAGE_B(128, 1, 0);
    asm volatile("s_waitcnt vmcnt(4)" ::: "memory");
    __builtin_amdgcn_s_barrier();

    // Steady state per iter (tiles t=2i in buf0, t+1 in buf1):
    //  P1 rd buf0k0, st A(t+1,k1)->b1k1   P5 rd buf1k0, st A(t+2,k1)->b0k1
    //  P2 rd buf0k0, st B(t+1,k1)         P6 rd buf1k0, st B(t+2,k1)
    //  P3 rd buf0k1, st A(t+2,k0)->b0k0   P7 rd buf1k1, st A(t+3,k0)->b1k0
    //  P4 rd buf0k1, st B(t+2,k0); vm4    P8 rd buf1k1, st B(t+3,k0); vm4
    // W-A-R: every stage targets a slot last read >=1 barrier earlier.
    // R-A-W: vm4@P4 covers P5/P7 data; vm4@P8 covers next-iter P1/P3 data.
    // Last iter stages harmless in-bounds garbage (<=8.5KB past W end; ws
    // has a 64KB pad).
    bf16x8_t af[4], bw[4];
#pragma unroll 1
    for (int it2 = 0; it2 < NTILE / 2; ++it2) {
        const int kt = it2 * 256;             // byte k-offset of tile t=2*it2
        PHASE(0, 0, 0, 1, STAGE_A(kt + 192, 1, 1), 0)
        PHASE(0, 0, 1, 0, STAGE_B(kt + 192, 1, 1), 0)
        PHASE(0, 1, 0, 1, STAGE_A(kt + 256, 0, 0), 0)
        PHASE(0, 1, 1, 0, STAGE_B(kt + 256, 0, 0), 1)
        PHASE(1, 0, 0, 1, STAGE_A(kt + 320, 0, 1), 0)
        PHASE(1, 0, 1, 0, STAGE_B(kt + 320, 0, 1), 0)
        PHASE(1, 1, 0, 1, STAGE_A(kt + 384, 1, 0), 0)
        PHASE(1, 1, 1, 0, STAGE_B(kt + 384, 1, 0), 1)
    }
    asm volatile("s_waitcnt vmcnt(0)" ::: "memory");  // drain garbage stages

    // Fused epilogue: gates in fp32 -> sigmoid/tanh -> read C -> write h,c.
    // C/D layout: col=lane&15, row=quad*4+reg (m89).
    const int isF32 = *flagp;
    const int col = bn * 64 + wc * 16 + lr;   // H column, 0..2047
    float bvv[4];
    bvv[0] = isF32 ? ((const float*)bi0)[col] : __bfloat162float(((const __hip_bfloat16*)bi0)[col]);
    bvv[1] = isF32 ? ((const float*)bi1)[col] : __bfloat162float(((const __hip_bfloat16*)bi1)[col]);
    bvv[2] = isF32 ? ((const float*)bi2)[col] : __bfloat162float(((const __hip_bfloat16*)bi2)[col]);
    bvv[3] = isF32 ? ((const float*)bi3)[col] : __bfloat162float(((const __hip_bfloat16*)bi3)[col]);

#pragma unroll
    for (int a = 0; a < 8; ++a) {
        const int rowBase = bm * 256 + wr * 128 + (a >> 2) * 64 + (a & 3) * 16 + quad * 4;
#pragma unroll
        for (int r = 0; r < 4; ++r) {
            const size_t idx = (size_t)(rowBase + r) * K_DIM + col;
            const float gi = acc[a][0][r] + bvv[0];
            const float go = acc[a][1][r] + bvv[1];
            const float gf = acc[a][2][r] + bvv[2];
            const float gc = acc[a][3][r] + bvv[3];
            const float cv = isF32 ? ((const float*)Cin)[idx]
                                   : bf_bits2f(((const unsigned short*)Cin)[idx]);
            const float it = sigmoid_f(gi);
            const float ot = sigmoid_f(go);
            const float ft = sigmoid_f(gf);
            const float ct = tanh_f(gc);
            const float nc = ft * cv + it * ct;
            const float nh = ot * tanh_f(nc);
            if (isF32) {
                ((float*)outp)[idx] = nh;
                ((float*)outp)[(size_t)BHT + idx] = nc;
            } else {
                ((unsigned short*)outp)[idx] = f2bf_bits(nh);
                ((unsigned short*)outp)[(size_t)BHT + idx] = f2bf_bits(nc);
            }
        }
    }
}

// ---------------------------------------------------------------------------
// Slow fallback GEMM (R3, passed): ds_write staging + in-kernel conversion.
// ---------------------------------------------------------------------------
__global__ __launch_bounds__(256) void gates_gemm_slow(
    const void* __restrict__ X, const void* __restrict__ Hm,
    const void* __restrict__ Wx0, const void* __restrict__ Wx1,
    const void* __restrict__ Wx2, const void* __restrict__ Wx3,
    const void* __restrict__ Wh0, const void* __restrict__ Wh1,
    const void* __restrict__ Wh2, const void* __restrict__ Wh3,
    const void* __restrict__ bi0, const void* __restrict__ bi1,
    const void* __restrict__ bi2, const void* __restrict__ bi3,
    const int* __restrict__ flagp, int m0,
    __hip_bfloat16* __restrict__ gates)
{
    __shared__ __align__(16) char lds[16384];
    const int isF32 = *flagp;
    const int esz   = isF32 ? 4 : 2;

    const int tid     = threadIdx.x;
    const int bm      = blockIdx.y;
    const int bn      = blockIdx.x;
    const int gate    = bn >> 4;
    const int nInGate = (bn & 15) << 7;

    const void* Wx = (gate == 0) ? Wx0 : (gate == 1) ? Wx1 : (gate == 2) ? Wx2 : Wx3;
    const void* Wh = (gate == 0) ? Wh0 : (gate == 1) ? Wh1 : (gate == 2) ? Wh2 : Wh3;
    const void* bs = (gate == 0) ? bi0 : (gate == 1) ? bi1 : (gate == 2) ? bi2 : bi3;

    const int ldRow = tid >> 2;
    const int sub   = tid & 3;
    const size_t rowStride = (size_t)K_DIM * esz;
    const size_t rowHalf   = 64 * rowStride;
    const char* aG  = (const char*)X  + (size_t)(m0 + bm * 128 + ldRow) * rowStride + (size_t)sub * 8 * esz;
    const char* hG  = (const char*)Hm + (size_t)(m0 + bm * 128 + ldRow) * rowStride + (size_t)sub * 8 * esz;
    const char* wxG = (const char*)Wx + (size_t)(nInGate + ldRow) * rowStride + (size_t)sub * 8 * esz;
    const char* whG = (const char*)Wh + (size_t)(nInGate + ldRow) * rowStride + (size_t)sub * 8 * esz;

    char* const dA0 = lds + tid * 16;
    char* const dA1 = lds + 4096 + tid * 16;
    char* const dB0 = lds + 8192 + tid * 16;
    char* const dB1 = lds + 12288 + tid * 16;
    const char* const AsB = lds;
    const char* const BsB = lds + 8192;

    const int lane = tid & 63;
    const int wave = tid >> 6;
    const int wm   = (wave & 1) << 6;
    const int wn   = (wave >> 1) << 6;
    const int lr   = lane & 15;
    const int quad = lane >> 4;

    int aOff[4], bOff[4];
#pragma unroll
    for (int i = 0; i < 4; ++i) {
        aOff[i] = ((wm + i * 16 + lr) * 32 + quad * 8) * 2;
        bOff[i] = ((wn + i * 16 + lr) * 32 + quad * 8) * 2;
    }

    floatx4_t acc[4][4];
#pragma unroll
    for (int mi = 0; mi < 4; ++mi)
#pragma unroll
        for (int ni = 0; ni < 4; ++ni)
            acc[mi][ni] = (floatx4_t){0.f, 0.f, 0.f, 0.f};

#pragma unroll 1
    for (int seg = 0; seg < 2; ++seg) {
        const char* ag = seg ? hG : aG;
        const char* bg = seg ? whG : wxG;
#pragma unroll 1
        for (int ke = 0; ke < K_DIM; ke += 32) {
            const size_t kb = (size_t)ke * esz;
            ushort8_t va0, va1, vb0, vb1;
            if (!isF32) {
                va0 = *reinterpret_cast<const ushort8_t*>(ag + kb);
                va1 = *reinterpret_cast<const ushort8_t*>(ag + rowHalf + kb);
                vb0 = *reinterpret_cast<const ushort8_t*>(bg + kb);
                vb1 = *reinterpret_cast<const ushort8_t*>(bg + rowHalf + kb);
            } else {
                const char* p; float4 f0, f1;
                p = ag + kb;           f0 = *reinterpret_cast<const float4*>(p);
                f1 = *reinterpret_cast<const float4*>(p + 16);
                va0 = (ushort8_t){f2bf_bits(f0.x), f2bf_bits(f0.y), f2bf_bits(f0.z), f2bf_bits(f0.w),
                                  f2bf_bits(f1.x), f2bf_bits(f1.y), f2bf_bits(f1.z), f2bf_bits(f1.w)};
                p = ag + rowHalf + kb; f0 = *reinterpret_cast<const float4*>(p);
                f1 = *reinterpret_cast<const float4*>(p + 16);
                va1 = (ushort8_t){f2bf_bits(f0.x), f2bf_bits(f0.y), f2bf_bits(f0.z), f2bf_bits(f0.w),
                                  f2bf_bits(f1.x), f2bf_bits(f1.y), f2bf_bits(f1.z), f2bf_bits(f1.w)};
                p = bg + kb;           f0 = *reinterpret_cast<const float4*>(p);
                f1 = *reinterpret_cast<const float4*>(p + 16);
                vb0 = (ushort8_t){f2bf_bits(f0.x), f2bf_bits(f0.y), f2bf_bits(f0.z), f2bf_bits(f0.w),
                                  f2bf_bits(f1.x), f2bf_bits(f1.y), f2bf_bits(f1.z), f2bf_bits(f1.w)};
                p = bg + rowHalf + kb; f0 = *reinterpret_cast<const float4*>(p);
                f1 = *reinterpret_cast<const float4*>(p + 16);
                vb1 = (ushort8_t){f2bf_bits(f0.x), f2bf_bits(f0.y), f2bf_bits(f0.z), f2bf_bits(f0.w),
                                  f2bf_bits(f1.x), f2bf_bits(f1.y), f2bf_bits(f1.z), f2bf_bits(f1.w)};
            }
            __syncthreads();
            *reinterpret_cast<ushort8_t*>(dA0) = va0;
            *reinterpret_cast<ushort8_t*>(dA1) = va1;
            *reinterpret_cast<ushort8_t*>(dB0) = vb0;
            *reinterpret_cast<ushort8_t*>(dB1) = vb1;
            __syncthreads();

            bf16x8_t af[4], bwv[4];
#pragma unroll
            for (int i = 0; i < 4; ++i) af[i] = *reinterpret_cast<const bf16x8_t*>(AsB + aOff[i]);
#pragma unroll
            for (int i = 0; i < 4; ++i) bwv[i] = *reinterpret_cast<const bf16x8_t*>(BsB + bOff[i]);
#pragma unroll
            for (int mi = 0; mi < 4; ++mi)
#pragma unroll
                for (int ni = 0; ni < 4; ++ni)
                    acc[mi][ni] = __builtin_amdgcn_mfma_f32_16x16x32_bf16(
                        af[mi], bwv[ni], acc[mi][ni], 0, 0, 0);
        }
    }

    float bv[4];
#pragma unroll
    for (int ni = 0; ni < 4; ++ni) {
        const int col = nInGate + wn + ni * 16 + lr;
        bv[ni] = isF32 ? ((const float*)bs)[col]
                       : __bfloat162float(((const __hip_bfloat16*)bs)[col]);
    }
#pragma unroll
    for (int mi = 0; mi < 4; ++mi) {
        const int rowBase = bm * 128 + wm + mi * 16 + quad * 4;
#pragma unroll
        for (int ni = 0; ni < 4; ++ni) {
            const size_t colBase = (size_t)gate * 2048 + nInGate + wn + ni * 16 + lr;
#pragma unroll
            for (int r = 0; r < 4; ++r)
                gates[(size_t)(rowBase + r) * NG + colBase] =
                    __float2bfloat16(acc[mi][ni][r] + bv[ni]);
        }
    }
}

// ---------------------------------------------------------------------------
// Pointwise LSTM combine (fallback path only).
// ---------------------------------------------------------------------------
__global__ __launch_bounds__(256) void lstm_pointwise_kernel(
    const unsigned short* __restrict__ gates,
    const void* __restrict__ Cin,
    void* __restrict__ out,
    const int* __restrict__ flagp, int m0)
{
    const int isF32 = *flagp;
    const int lidx = (blockIdx.x * 256 + threadIdx.x) * 4;
    const int b = lidx >> 11;
    const int j = lidx & 2047;
    const unsigned short* g = gates + (size_t)b * NG + j;
    const size_t gidx = (size_t)m0 * 2048 + (size_t)lidx;

    const ushort4 ui = *reinterpret_cast<const ushort4*>(g);
    const ushort4 uo = *reinterpret_cast<const ushort4*>(g + 2048);
    const ushort4 uf = *reinterpret_cast<const ushort4*>(g + 4096);
    const ushort4 uc = *reinterpret_cast<const ushort4*>(g + 6144);
    const float gi[4] = {bf_bits2f(ui.x), bf_bits2f(ui.y), bf_bits2f(ui.z), bf_bits2f(ui.w)};
    const float go[4] = {bf_bits2f(uo.x), bf_bits2f(uo.y), bf_bits2f(uo.z), bf_bits2f(uo.w)};
    const float gf[4] = {bf_bits2f(uf.x), bf_bits2f(uf.y), bf_bits2f(uf.z), bf_bits2f(uf.w)};
    const float gc[4] = {bf_bits2f(uc.x), bf_bits2f(uc.y), bf_bits2f(uc.z), bf_bits2f(uc.w)};

    float cv[4];
    if (isF32) {
        const float4 c4 = *reinterpret_cast<const float4*>((const float*)Cin + gidx);
        cv[0] = c4.x; cv[1] = c4.y; cv[2] = c4.z; cv[3] = c4.w;
    } else {
        const ushort4 u = *reinterpret_cast<const ushort4*>((const unsigned short*)Cin + gidx);
        cv[0] = bf_bits2f(u.x); cv[1] = bf_bits2f(u.y);
        cv[2] = bf_bits2f(u.z); cv[3] = bf_bits2f(u.w);
    }

    float nh[4], nc[4];
#pragma unroll
    for (int k = 0; k < 4; ++k) {
        const float it = sigmoid_f(gi[k]);
        const float ot = sigmoid_f(go[k]);
        const float ft = sigmoid_f(gf[k]);
        const float ct = tanh_f(gc[k]);
        nc[k] = ft * cv[k] + it * ct;
        nh[k] = ot * tanh_f(nc[k]);
    }

    if (isF32) {
        float* oH = (float*)out;
        float* oC = oH + (size_t)BHT;
        *reinterpret_cast<float4*>(oH + gidx) = make_float4(nh[0], nh[1], nh[2], nh[3]);
        *reinterpret_cast<float4*>(oC + gidx) = make_float4(nc[0], nc[1], nc[2], nc[3]);
    } else {
        unsigned short* oH = (unsigned short*)out;
        unsigned short* oC = oH + (size_t)BHT;
        *reinterpret_cast<ushort4*>(oH + gidx) =
            make_ushort4(f2bf_bits(nh[0]), f2bf_bits(nh[1]), f2bf_bits(nh[2]), f2bf_bits(nh[3]));
        *reinterpret_cast<ushort4*>(oC + gidx) =
            make_ushort4(f2bf_bits(nc[0]), f2bf_bits(nc[1]), f2bf_bits(nc[2]), f2bf_bits(nc[3]));
    }
}

extern "C" void kernel_launch(void* const* d_in, const int* in_sizes, int n_in,
                              void* d_out, int out_size, void* d_ws, size_t ws_size,
                              hipStream_t stream) {
    (void)in_sizes; (void)n_in; (void)out_size;
    const void* X   = d_in[0];
    const void* Hm  = d_in[1];
    const void* C   = d_in[2];
    const void* Wxi = d_in[3];
    const void* Wxo = d_in[4];
    const void* Wxf = d_in[5];
    const void* Wxc = d_in[6];
    const void* bi  = d_in[7];
    const void* bo  = d_in[8];
    const void* bfp = d_in[9];
    const void* bc  = d_in[10];
    const void* Whi = d_in[11];
    const void* Who = d_in[12];
    const void* Whf = d_in[13];
    const void* Whc = d_in[14];

    const size_t flagOff = (ws_size - 4) & ~(size_t)15;
    int* flag = (int*)((char*)d_ws + flagOff);
    const dim3 blk(256);

    dtype_probe_kernel<<<1, 64, 0, stream>>>((const unsigned int*)X, flag);

    if (ws_size >= FAST_NEED) {
        unsigned short* conv = (unsigned short*)d_ws;

        SrcPtrs sp;
        sp.p[0] = X;  sp.p[1] = Hm;
        sp.p[2] = Wxi; sp.p[3] = Wxo; sp.p[4] = Wxf; sp.p[5] = Wxc;
        sp.p[6] = Whi; sp.p[7] = Who; sp.p[8] = Whf; sp.p[9] = Whc;
        convert_kernel<<<dim3(CONV_TOTAL / 2048), blk, 0, stream>>>(sp, conv, flag);

        gates_gemm_fast<<<dim3(512), dim3(512), 0, stream>>>(
            conv, bi, bo, bfp, bc, C, flag, d_out);
    } else {
        __hip_bfloat16* gates = (__hip_bfloat16*)d_ws;
        int rows = B_DIM;
        while ((size_t)rows * NG * 2 > flagOff && rows > 128) rows >>= 1;
        for (int m0 = 0; m0 < B_DIM; m0 += rows) {
            gates_gemm_slow<<<dim3(64, rows / 128), blk, 0, stream>>>(
                X, Hm, Wxi, Wxo, Wxf, Wxc, Whi, Who, Whf, Whc,
                bi, bo, bfp, bc, flag, m0, gates);
            lstm_pointwise_kernel<<<dim3(rows * 2048 / 1024), blk, 0, stream>>>(
                (const unsigned short*)gates, C, d_out, flag, m0);
        }
    }
}